// Round 7
// baseline (1182.671 us; speedup 1.0000x reference)
//
#include <hip/hip_runtime.h>

#define DD 64
#define HH 256
#define WW 256
#define HW (HH * WW)      // 65536
#define NVOX (DD * HW)    // 4194304

#define TS 32             // output tile (H and W)
#define DR 36             // deriv region = TS+4 (row stride 36, even)
#define HPH 40            // hbuf row stride in HALFS (bank-spread: 2-way free)
#define CHB 16            // depth chunk: 4 chunks -> grid z=16 -> 1024 blocks = 4/CU
#define NT 320            // 5 waves: 289 conv1 patches <= 320 -> 1 patch/thread
#define NPF 5             // staging slots = ceil(DR*DR/NT) (4 full + 16)

typedef __fp16 half2v __attribute__((ext_vector_type(2)));

#if __has_builtin(__builtin_amdgcn_fdot2)
#define FDOT2(a, b, c) __builtin_amdgcn_fdot2((a), (b), (c), false)
#else
#define FDOT2(a, b, c) \
  fmaf((float)(a).x, (float)(b).x, fmaf((float)(a).y, (float)(b).y, (c)))
#endif

// ---------------------------------------------------------------------------
// Kernel A: corr[h,w] = (sino[h,w] - sum_d t[d,h,w]) / DD
// ---------------------------------------------------------------------------
__global__ __launch_bounds__(256) void k_corr(const float* __restrict__ t,
                                              const float* __restrict__ sino,
                                              float* __restrict__ corr) {
  int idx = blockIdx.x * 256 + threadIdx.x;  // 0..HW-1
  float s = 0.f;
#pragma unroll 8
  for (int d = 0; d < DD; ++d) s += t[d * HW + idx];
  corr[idx] = (sino[idx] - s) * (1.0f / DD);
}

// ---------------------------------------------------------------------------
// Kernel B (R10): R8 structure, 320 threads.
// R9 post-mortem: kernel is VALU-issue-bound (dur ~= VALUBusy*dur/(1-stall));
// barrier count is NOT the lever (R9: half the barriers, worse). Biggest
// identified overhead: conv1's 289-patches-on-256-threads imbalance -- waves
// 0-1 built a SECOND full 24-read window for the 33 leftover patches (phase2)
// while wave 3 idled at the barrier. With 5 waves (320 thr): exactly one
// conv1 patch per thread, phase2 gone. conv2/store owned by tid<256; wave 4
// idles there (hidden by 4 blocks x 5 waves = 20 waves/CU). Staging spread
// over 320 threads (NPF=5).
// ---------------------------------------------------------------------------
__global__ __launch_bounds__(NT, 5) void k_blocks(
    const float* __restrict__ t, const float* __restrict__ corr,
    float* __restrict__ p, float* __restrict__ q, float* __restrict__ s_,
    float* __restrict__ zb,
    const float* __restrict__ W1g, const float* __restrict__ B1g,
    const float* __restrict__ W2g, const float* __restrict__ B2g,
    const float* __restrict__ ntx, const float* __restrict__ nty,
    const float* __restrict__ ntz, const float* __restrict__ nt, int c) {
  __shared__ __align__(16) float dbuf[3][DR][DR];        // 15552 B
  __shared__ __align__(16) __fp16 hbuf[8][34][HPH];      // 21760 B
  __shared__ __align__(8) half2v wpkl[72];               // 288 B (37600 total)

  const int b = blockIdx.z & 3;
  const int D0 = (blockIdx.z >> 2) * CHB;           // 0,16,32,48
  const int Dend = (D0 + CHB < DD) ? (D0 + CHB) : DD;
  const int ty0 = blockIdx.y * TS;
  const int tx0 = blockIdx.x * TS;
  const int tid = threadIdx.x;
  const bool owner = (tid < 256);                   // conv2 / store ownership
  const bool edgeT = (ty0 == 0) || (ty0 == HH - TS) || (tx0 == 0) || (tx0 == WW - TS);

  const float* w1 = W1g + b * 216;  // [8][3][3][3]
  const float* w2 = W2g + b * 216;  // [8][3][3][3] (W2 shape (4,1,8,3,3,3))
  float b1[8];
#pragma unroll
  for (int ch = 0; ch < 8; ++ch) b1[ch] = B1g[b * 8 + ch];
  const float b2 = B2g[b];
  const float coef = (b == 0) ? ntx[c] : (b == 1) ? nty[c] : (b == 2) ? ntz[c] : nt[c];
  const float* prevBuf = (b == 0) ? p : (b == 1) ? q : (b == 2) ? s_ : t;
  float* outBuf = (b == 0) ? p : (b == 1) ? q : (b == 2) ? s_ : zb;
  const bool zeroPrev = (c == 0) && (b < 3);
  const int strideA = (b == 0) ? 1 : (b == 1) ? WW : HW;

  auto dslot = [](int f) { return (f + 6) % 3; };

  // ---- pack conv2 weights (kx0,kx1) as half2 into LDS (once per block)
  if (tid < 72) {
    int ch = tid / 9, pr = tid - ch * 9;     // pr = kz*3+ky
    const float* w = w2 + ch * 27 + pr * 3;
    half2v hv;
    hv.x = (__fp16)w[0];
    hv.y = (__fp16)w[1];
    wpkl[tid] = hv;
  }

  // ---- hoisted per-slot geometry (f-invariant): cbt, load-mask bit, corr diff
  int cbt[NPF];
  float dC[NPF];
  unsigned mbits = 0;
#pragma unroll
  for (int k = 0; k < NPF; ++k) {
    int i = tid + k * NT;
    int iy = i / DR, ix = i - iy * DR;
    int gy = ty0 - 2 + iy, gx = tx0 - 2 + ix;
    bool inb = (i < DR * DR) && ((unsigned)gy < HH) && ((unsigned)gx < WW);
    int cb = gy * WW + gx;
    cbt[k] = cb;
    bool m;
    float d = 0.f;
    if (b == 0) {
      m = inb && (gx + 1 < WW);
      if (m) d = corr[cb + 1] - corr[cb];
    } else if (b == 1) {
      m = inb && (gy + 1 < HH);
      if (m) d = corr[cb + WW] - corr[cb];
    } else if (b == 2) {
      m = inb;
    } else {
      m = inb;
      if (m) d = corr[cb];
    }
    dC[k] = d;
    if (m) mbits |= (1u << k);
  }

  // ---- prefetch state: raw global t values for deriv plane f
  float pA0[NPF], pA1[NPF];

  auto issue_loads = [&](int f) {
    const bool fok = (f >= 0) && (f < DD) && (b != 2 || (f + 1 < DD));
    const int fb = f * HW;
#pragma unroll
    for (int k = 0; k < NPF; ++k) {
      pA0[k] = 0.f; pA1[k] = 0.f;
      if (fok && ((mbits >> k) & 1u)) {
        const float* base = t + fb + cbt[k];
        pA0[k] = base[0];
        if (b != 3) pA1[k] = base[strideA];
      }
    }
  };
  auto write_deriv = [&](int f) {
    float* dst = &dbuf[dslot(f)][0][0];
#pragma unroll
    for (int k = 0; k < NPF; ++k) {
      if (k < NPF - 1 || tid < (DR * DR - (NPF - 1) * NT)) {  // i < 1296
        float v = (b == 3) ? (pA0[k] + dC[k]) : ((pA1[k] - pA0[k]) + dC[k]);
        dst[tid + k * NT] = v;
      }
    }
  };

  // ---- conv1 for one 2x2 hidden patch at (jy,jx), all 8 channels
  auto conv1_patch = [&](const float* d0, const float* d1, const float* d2,
                         int jy, int jx) {
    float win[3][4][4];
#pragma unroll
    for (int r = 0; r < 4; ++r) {
      int off = (jy + r) * DR + jx;
      const float2* r0 = (const float2*)(d0 + off);
      const float2* r1 = (const float2*)(d1 + off);
      const float2* r2 = (const float2*)(d2 + off);
      float2 a, bb;
      a = r0[0]; bb = r0[1];
      win[0][r][0] = a.x; win[0][r][1] = a.y; win[0][r][2] = bb.x; win[0][r][3] = bb.y;
      a = r1[0]; bb = r1[1];
      win[1][r][0] = a.x; win[1][r][1] = a.y; win[1][r][2] = bb.x; win[1][r][3] = bb.y;
      a = r2[0]; bb = r2[1];
      win[2][r][0] = a.x; win[2][r][1] = a.y; win[2][r][2] = bb.x; win[2][r][3] = bb.y;
    }
    bool in00 = true, in01 = true, in10 = true, in11 = true;
    if (edgeT) {
      int gy0 = ty0 - 1 + jy, gx0 = tx0 - 1 + jx;
      in00 = ((unsigned)gy0 < HH) && ((unsigned)gx0 < WW);
      in01 = ((unsigned)gy0 < HH) && ((unsigned)(gx0 + 1) < WW);
      in10 = ((unsigned)(gy0 + 1) < HH) && ((unsigned)gx0 < WW);
      in11 = ((unsigned)(gy0 + 1) < HH) && ((unsigned)(gx0 + 1) < WW);
    }
#pragma unroll 2
    for (int ch = 0; ch < 8; ++ch) {
      float bia = b1[ch];
      float a00 = bia, a01 = bia, a10 = bia, a11 = bia;
      const float* wch = w1 + ch * 27;
#pragma unroll
      for (int kz = 0; kz < 3; ++kz)
#pragma unroll
        for (int ky = 0; ky < 3; ++ky)
#pragma unroll
          for (int kx = 0; kx < 3; ++kx) {
            float wv = wch[kz * 9 + ky * 3 + kx];
            a00 = fmaf(wv, win[kz][ky][kx], a00);
            a01 = fmaf(wv, win[kz][ky][kx + 1], a01);
            a10 = fmaf(wv, win[kz][ky + 1][kx], a10);
            a11 = fmaf(wv, win[kz][ky + 1][kx + 1], a11);
          }
      float r00 = fmaxf(a00, 0.f), r01 = fmaxf(a01, 0.f);
      float r10 = fmaxf(a10, 0.f), r11 = fmaxf(a11, 0.f);
      if (edgeT) {  // block-uniform branch: interior tiles skip the masking
        r00 = in00 ? r00 : 0.f;
        r01 = in01 ? r01 : 0.f;
        r10 = in10 ? r10 : 0.f;
        r11 = in11 ? r11 : 0.f;
      }
      *(half2v*)&hbuf[ch][jy][jx]     = __builtin_amdgcn_cvt_pkrtz(r00, r01);
      *(half2v*)&hbuf[ch][jy + 1][jx] = __builtin_amdgcn_cvt_pkrtz(r10, r11);
    }
  };

  // ---- hidden plane e -> hbuf: 289 patches, exactly one per thread
  auto comp_hidden = [&](int e) {
    if (tid < 289) {
      const float* d0 = &dbuf[dslot(e - 1)][0][0];
      const float* d1 = &dbuf[dslot(e)][0][0];
      const float* d2 = &dbuf[dslot(e + 1)][0][0];
      int prr = tid / 17, pcc = tid - prr * 17;
      conv1_patch(d0, d1, d2, prr * 2, pcc * 2);
    }
  };

  const int txi = tid & 15, tyi = (tid >> 4) & 15;
  const int px0 = txi * 2, py0 = tyi * 2;

  // register ring: aM = plane e-1, aC = plane e, aP = plane e+1
  float aM[2][2], aC[2][2], aP[2][2];
#pragma unroll
  for (int i = 0; i < 2; ++i)
#pragma unroll
    for (int j = 0; j < 2; ++j) { aM[i][j] = b2; aC[i][j] = b2; aP[i][j] = b2; }

  // prologue: deriv planes D0-2, D0-1, D0 (out-of-range -> zeros)
  issue_loads(D0 - 2); write_deriv(D0 - 2);
  issue_loads(D0 - 1); write_deriv(D0 - 1);
  issue_loads(D0);     write_deriv(D0);
  __syncthreads();  // also fences wpkl pack

  for (int e = D0 - 1; e <= Dend; ++e) {
    const bool live = (e >= 0 && e < DD);
    // prefetch next deriv plane (global -> regs); overlaps conv1 compute
    issue_loads(e + 2);
    // prefetch prev-state operand for this iteration's output store
    float2 pr0, pr1;
    pr0.x = pr0.y = pr1.x = pr1.y = 0.f;
    const int d = e - 1;
    const bool doStore = (e >= D0 + 1) && owner;
    if (doStore && !zeroPrev) {
      size_t v0 = (size_t)d * HW + (size_t)(ty0 + py0) * WW + tx0 + px0;
      pr0 = *(const float2*)&prevBuf[v0];
      pr1 = *(const float2*)&prevBuf[v0 + WW];
    }
    if (live) comp_hidden(e);
    __syncthreads();  // hbuf RAW ready; all conv1 dbuf reads done
    if (live && owner) {
      // scatter hidden e into aP(kz=0 -> e+1), aC(kz=1 -> e), aM(kz=2 -> e-1)
      // conv2 via dot2: per output row pair, dot2 over (kx0,kx1) + scalar kx2.
#pragma unroll 1
      for (int ch = 0; ch < 8; ++ch) {  // unroll 1: cap live set
        const float* wch = w2 + ch * 27;
        const half2v* wrow = &wpkl[ch * 9];
        half2v H0[4], HPv[4];
        float c0[4], c1[4];
#pragma unroll
        for (int r = 0; r < 4; ++r) {
          const __fp16* hp = &hbuf[ch][py0 + r][px0];
          half2v h0 = *(const half2v*)hp;        // taps x: px0, px0+1
          half2v h1 = *(const half2v*)(hp + 2);  // taps x: px0+2, px0+3
          unsigned u0, u1;
          __builtin_memcpy(&u0, &h0, 4);
          __builtin_memcpy(&u1, &h1, 4);
          unsigned pm = (u1 << 16) | (u0 >> 16);  // (px0+1, px0+2) -> v_alignbit
          half2v hpv;
          __builtin_memcpy(&hpv, &pm, 4);
          H0[r] = h0; HPv[r] = hpv;
          c0[r] = (float)h1.x;  // scalar tap for j=0 (kx2)
          c1[r] = (float)h1.y;  // scalar tap for j=1 (kx2)
        }
#pragma unroll
        for (int ky = 0; ky < 3; ++ky)
#pragma unroll
          for (int i = 0; i < 2; ++i) {
            const int r = i + ky;
            const half2v hA = H0[r], hB = HPv[r];
            const float s0 = c0[r], s1 = c1[r];
            {
              half2v wv = wrow[ky];            // kz=0 pair (w_kx0,w_kx1)
              float ws = wch[ky * 3 + 2];      // kz=0 w_kx2
              aP[i][0] = FDOT2(hA, wv, aP[i][0]);
              aP[i][0] = fmaf(ws, s0, aP[i][0]);
              aP[i][1] = FDOT2(hB, wv, aP[i][1]);
              aP[i][1] = fmaf(ws, s1, aP[i][1]);
            }
            {
              half2v wv = wrow[3 + ky];        // kz=1
              float ws = wch[9 + ky * 3 + 2];
              aC[i][0] = FDOT2(hA, wv, aC[i][0]);
              aC[i][0] = fmaf(ws, s0, aC[i][0]);
              aC[i][1] = FDOT2(hB, wv, aC[i][1]);
              aC[i][1] = fmaf(ws, s1, aC[i][1]);
            }
            {
              half2v wv = wrow[6 + ky];        // kz=2
              float ws = wch[18 + ky * 3 + 2];
              aM[i][0] = FDOT2(hA, wv, aM[i][0]);
              aM[i][0] = fmaf(ws, s0, aM[i][0]);
              aM[i][1] = FDOT2(hB, wv, aM[i][1]);
              aM[i][1] = fmaf(ws, s1, aM[i][1]);
            }
          }
      }
    }
    // deriv plane e+2 -> LDS (slot (e+2)%3 == (e-1)%3, freed by the sync)
    write_deriv(e + 2);
    // plane e-1 complete after hidden e's kz=2 contribution
    if (doStore) {
      size_t v0 = (size_t)d * HW + (size_t)(ty0 + py0) * WW + tx0 + px0;
      float2 o0, o1;
      o0.x = pr0.x + coef * (pr0.x - aM[0][0]);
      o0.y = pr0.y + coef * (pr0.y - aM[0][1]);
      o1.x = pr1.x + coef * (pr1.x - aM[1][0]);
      o1.y = pr1.y + coef * (pr1.y - aM[1][1]);
      *(float2*)&outBuf[v0] = o0;
      *(float2*)&outBuf[v0 + WW] = o1;
    }
    // rotate ring (name rotation: no dynamic register indexing)
#pragma unroll
    for (int i = 0; i < 2; ++i)
#pragma unroll
      for (int j = 0; j < 2; ++j) {
        aM[i][j] = aC[i][j]; aC[i][j] = aP[i][j]; aP[i][j] = b2;
      }
    __syncthreads();  // fences dbuf RAW + hbuf WAR for next iteration
  }
}

// ---------------------------------------------------------------------------
// Kernel C: t_next = fdiff_t(p,x) + fdiff_t(q,y) + fdiff_t(s,z) + zb
// ---------------------------------------------------------------------------
__global__ __launch_bounds__(256) void k_combine(
    const float* __restrict__ p, const float* __restrict__ q,
    const float* __restrict__ s_, const float* __restrict__ zb,
    float* __restrict__ tn) {
  int idx = blockIdx.x * 256 + threadIdx.x;
  int x = idx & (WW - 1);
  int y = (idx >> 8) & (HH - 1);
  int d = idx >> 16;
  float v = zb[idx];
  v += (x > 0 ? p[idx - 1] : 0.f) - (x < WW - 1 ? p[idx] : 0.f);
  v += (y > 0 ? q[idx - WW] : 0.f) - (y < HH - 1 ? q[idx] : 0.f);
  v += (d > 0 ? s_[idx - HW] : 0.f) - (d < DD - 1 ? s_[idx] : 0.f);
  tn[idx] = v;
}

// ---------------------------------------------------------------------------
extern "C" void kernel_launch(void* const* d_in, const int* in_sizes, int n_in,
                              void* d_out, int out_size, void* d_ws, size_t ws_size,
                              hipStream_t stream) {
  const float* image = (const float*)d_in[0];
  const float* sino  = (const float*)d_in[1];
  const float* W1    = (const float*)d_in[2];
  const float* B1    = (const float*)d_in[3];
  const float* W2    = (const float*)d_in[4];
  const float* B2    = (const float*)d_in[5];
  const float* ntx   = (const float*)d_in[6];
  const float* nty   = (const float*)d_in[7];
  const float* ntz   = (const float*)d_in[8];
  const float* nt    = (const float*)d_in[9];
  float* out = (float*)d_out;

  // workspace layout: corr(HW) | p | q | s | zb  -> 67.4 MB total
  float* corr = (float*)d_ws;
  float* p  = corr + HW;
  float* q  = p + NVOX;
  float* s_ = q + NVOX;
  float* zb = s_ + NVOX;

  // outs[0] = image
  hipMemcpyAsync(out, image, (size_t)NVOX * sizeof(float),
                 hipMemcpyDeviceToDevice, stream);

  for (int c = 0; c < 3; ++c) {
    const float* t = out + (size_t)c * NVOX;
    float* tn = out + (size_t)(c + 1) * NVOX;
    k_corr<<<HW / 256, 256, 0, stream>>>(t, sino, corr);
    // z: 4 basic-blocks x 4 depth chunks -> 1024 blocks = 4 WG/CU (320 thr)
    k_blocks<<<dim3(WW / TS, HH / TS, 16), NT, 0, stream>>>(
        t, corr, p, q, s_, zb, W1, B1, W2, B2, ntx, nty, ntz, nt, c);
    k_combine<<<NVOX / 256, 256, 0, stream>>>(p, q, s_, zb, tn);
  }
}

// Round 8
// 970.474 us; speedup vs baseline: 1.2187x; 1.2187x over previous
//
#include <hip/hip_runtime.h>

#define DD 64
#define HH 256
#define WW 256
#define HW (HH * WW)      // 65536
#define NVOX (DD * HW)    // 4194304

#define TS 32             // output tile (H and W)
#define DR 36             // deriv region = TS+4 (row stride 36, even)
#define HPH 40            // hbuf row stride in HALFS (bank-spread: 2-way free)
#define CHB 16            // depth chunk: 4 chunks -> grid z=16
#define NPF 6             // prefetch slots = ceil(DR*DR/256)

typedef __fp16 half2v __attribute__((ext_vector_type(2)));

// ---------------------------------------------------------------------------
// Kernel A: corr[h,w] = (sino[h,w] - sum_d t[d,h,w]) / DD
// ---------------------------------------------------------------------------
__global__ __launch_bounds__(256) void k_corr(const float* __restrict__ t,
                                              const float* __restrict__ sino,
                                              float* __restrict__ corr) {
  int idx = blockIdx.x * 256 + threadIdx.x;  // 0..HW-1
  float s = 0.f;
#pragma unroll 8
  for (int d = 0; d < DD; ++d) s += t[d * HW + idx];
  corr[idx] = (sino[idx] - s) * (1.0f / DD);
}

// ---------------------------------------------------------------------------
// Kernel B (R11): R7c structure EXACTLY, but __launch_bounds__(256, 2).
// Cross-round evidence: VGPR 48 -> 373us, 64 -> 305, 84 -> 306. conv1's live
// set is ~107 VGPRs (win 48 + prefetch 12 + geom 12 + acc/bias/addr ~35);
// every prior config was allocated below it, forcing the compiler to
// rematerialize win from LDS inside the FMA chain (the unexplained ~2.5x
// cycle inflation; R6 3blk/84reg == R7 4blk/64reg because less-remat and
// less-occupancy cancelled). (256,2) lets the allocator hold the full live
// set; occupancy cost of 2 blocks/CU bounded at ~+3% by R9.
// ---------------------------------------------------------------------------
__global__ __launch_bounds__(256, 2) void k_blocks(
    const float* __restrict__ t, const float* __restrict__ corr,
    float* __restrict__ p, float* __restrict__ q, float* __restrict__ s_,
    float* __restrict__ zb,
    const float* __restrict__ W1g, const float* __restrict__ B1g,
    const float* __restrict__ W2g, const float* __restrict__ B2g,
    const float* __restrict__ ntx, const float* __restrict__ nty,
    const float* __restrict__ ntz, const float* __restrict__ nt, int c) {
  __shared__ __align__(16) float dbuf[3][DR][DR];        // 15552 B
  __shared__ __align__(16) __fp16 hbuf[8][34][HPH];      // 21760 B  (37312 total)

  const int b = blockIdx.z & 3;
  const int D0 = (blockIdx.z >> 2) * CHB;           // 0,16,32,48
  const int Dend = (D0 + CHB < DD) ? (D0 + CHB) : DD;
  const int ty0 = blockIdx.y * TS;
  const int tx0 = blockIdx.x * TS;
  const int tid = threadIdx.x;

  const float* w1 = W1g + b * 216;  // [8][3][3][3]
  const float* w2 = W2g + b * 216;  // [8][3][3][3] (W2 shape (4,1,8,3,3,3))
  float b1[8];
#pragma unroll
  for (int ch = 0; ch < 8; ++ch) b1[ch] = B1g[b * 8 + ch];
  const float b2 = B2g[b];
  const float coef = (b == 0) ? ntx[c] : (b == 1) ? nty[c] : (b == 2) ? ntz[c] : nt[c];
  const float* prevBuf = (b == 0) ? p : (b == 1) ? q : (b == 2) ? s_ : t;
  float* outBuf = (b == 0) ? p : (b == 1) ? q : (b == 2) ? s_ : zb;
  const bool zeroPrev = (c == 0) && (b < 3);
  const int strideA = (b == 0) ? 1 : (b == 1) ? WW : HW;

  auto dslot = [](int f) { return (f + 6) % 3; };

  // ---- hoisted per-slot geometry (f-invariant): cbt, load-mask bit, corr diff
  int cbt[NPF];
  float dC[NPF];
  unsigned mbits = 0;
#pragma unroll
  for (int k = 0; k < NPF; ++k) {
    int i = tid + k * 256;
    int iy = i / DR, ix = i - iy * DR;
    int gy = ty0 - 2 + iy, gx = tx0 - 2 + ix;
    bool inb = (i < DR * DR) && ((unsigned)gy < HH) && ((unsigned)gx < WW);
    int cb = gy * WW + gx;
    cbt[k] = cb;
    bool m;
    float d = 0.f;
    if (b == 0) {
      m = inb && (gx + 1 < WW);
      if (m) d = corr[cb + 1] - corr[cb];
    } else if (b == 1) {
      m = inb && (gy + 1 < HH);
      if (m) d = corr[cb + WW] - corr[cb];
    } else if (b == 2) {
      m = inb;
    } else {
      m = inb;
      if (m) d = corr[cb];
    }
    dC[k] = d;
    if (m) mbits |= (1u << k);
  }

  // ---- prefetch state: raw global t values for deriv plane f
  float pA0[NPF], pA1[NPF];

  auto issue_loads = [&](int f) {
    const bool fok = (f >= 0) && (f < DD) && (b != 2 || (f + 1 < DD));
    const int fb = f * HW;
#pragma unroll
    for (int k = 0; k < NPF; ++k) {
      pA0[k] = 0.f; pA1[k] = 0.f;
      if (fok && ((mbits >> k) & 1u)) {
        const float* base = t + fb + cbt[k];
        pA0[k] = base[0];
        if (b != 3) pA1[k] = base[strideA];
      }
    }
  };
  auto write_deriv = [&](int f) {
    float* dst = &dbuf[dslot(f)][0][0];
#pragma unroll
    for (int k = 0; k < NPF; ++k) {
      if (k < 5 || tid < (DR * DR - 5 * 256)) {  // i < 1296
        float v = (b == 3) ? (pA0[k] + dC[k]) : ((pA1[k] - pA0[k]) + dC[k]);
        dst[tid + k * 256] = v;
      }
    }
  };

  // ---- conv1 for one 2x2 hidden patch at (jy,jx), channels [ch0,ch1)
  auto conv1_patch = [&](const float* d0, const float* d1, const float* d2,
                         int jy, int jx, int ch0, int ch1) {
    float win[3][4][4];
#pragma unroll
    for (int r = 0; r < 4; ++r) {
      int off = (jy + r) * DR + jx;
      const float2* r0 = (const float2*)(d0 + off);
      const float2* r1 = (const float2*)(d1 + off);
      const float2* r2 = (const float2*)(d2 + off);
      float2 a, bb;
      a = r0[0]; bb = r0[1];
      win[0][r][0] = a.x; win[0][r][1] = a.y; win[0][r][2] = bb.x; win[0][r][3] = bb.y;
      a = r1[0]; bb = r1[1];
      win[1][r][0] = a.x; win[1][r][1] = a.y; win[1][r][2] = bb.x; win[1][r][3] = bb.y;
      a = r2[0]; bb = r2[1];
      win[2][r][0] = a.x; win[2][r][1] = a.y; win[2][r][2] = bb.x; win[2][r][3] = bb.y;
    }
    int gy0 = ty0 - 1 + jy, gx0 = tx0 - 1 + jx;
    bool in00 = ((unsigned)gy0 < HH) && ((unsigned)gx0 < WW);
    bool in01 = ((unsigned)gy0 < HH) && ((unsigned)(gx0 + 1) < WW);
    bool in10 = ((unsigned)(gy0 + 1) < HH) && ((unsigned)gx0 < WW);
    bool in11 = ((unsigned)(gy0 + 1) < HH) && ((unsigned)(gx0 + 1) < WW);
#pragma unroll 2
    for (int ch = ch0; ch < ch1; ++ch) {
      float bia = b1[ch];
      float a00 = bia, a01 = bia, a10 = bia, a11 = bia;
      const float* wch = w1 + ch * 27;
#pragma unroll
      for (int kz = 0; kz < 3; ++kz)
#pragma unroll
        for (int ky = 0; ky < 3; ++ky)
#pragma unroll
          for (int kx = 0; kx < 3; ++kx) {
            float wv = wch[kz * 9 + ky * 3 + kx];
            a00 = fmaf(wv, win[kz][ky][kx], a00);
            a01 = fmaf(wv, win[kz][ky][kx + 1], a01);
            a10 = fmaf(wv, win[kz][ky + 1][kx], a10);
            a11 = fmaf(wv, win[kz][ky + 1][kx + 1], a11);
          }
      half2v h0, h1;
      h0.x = (__fp16)(in00 ? fmaxf(a00, 0.f) : 0.f);
      h0.y = (__fp16)(in01 ? fmaxf(a01, 0.f) : 0.f);
      h1.x = (__fp16)(in10 ? fmaxf(a10, 0.f) : 0.f);
      h1.y = (__fp16)(in11 ? fmaxf(a11, 0.f) : 0.f);
      *(half2v*)&hbuf[ch][jy][jx] = h0;
      *(half2v*)&hbuf[ch][jy + 1][jx] = h1;
    }
  };

  // ---- hidden plane e -> hbuf. Balanced: phase1 256 patches (1/thread),
  // phase2 = 33 leftover patches x 4 ch-pairs = 132 tasks (1/thread).
  auto comp_hidden = [&](int e) {
    const float* d0 = &dbuf[dslot(e - 1)][0][0];
    const float* d1 = &dbuf[dslot(e)][0][0];
    const float* d2 = &dbuf[dslot(e + 1)][0][0];
    {
      int prr = tid / 17, pcc = tid - prr * 17;     // patches 0..255
      conv1_patch(d0, d1, d2, prr * 2, pcc * 2, 0, 8);
    }
    if (tid < 132) {                                 // patches 256..288
      int m = tid >> 2, chp = (tid & 3) << 1;
      int pi = 256 + m;
      int prr = pi / 17, pcc = pi - prr * 17;
      conv1_patch(d0, d1, d2, prr * 2, pcc * 2, chp, chp + 2);
    }
  };

  const int txi = tid & 15, tyi = tid >> 4;
  const int px0 = txi * 2, py0 = tyi * 2;

  // register ring: aM = plane e-1, aC = plane e, aP = plane e+1
  float aM[2][2], aC[2][2], aP[2][2];
#pragma unroll
  for (int i = 0; i < 2; ++i)
#pragma unroll
    for (int j = 0; j < 2; ++j) { aM[i][j] = b2; aC[i][j] = b2; aP[i][j] = b2; }

  // prologue: deriv planes D0-2, D0-1, D0 (out-of-range -> zeros)
  issue_loads(D0 - 2); write_deriv(D0 - 2);
  issue_loads(D0 - 1); write_deriv(D0 - 1);
  issue_loads(D0);     write_deriv(D0);
  __syncthreads();

  for (int e = D0 - 1; e <= Dend; ++e) {
    const bool live = (e >= 0 && e < DD);
    // prefetch next deriv plane (global -> regs); overlaps conv1 compute
    issue_loads(e + 2);
    // prefetch prev-state operand for this iteration's output store
    float2 pr0, pr1;
    pr0.x = pr0.y = pr1.x = pr1.y = 0.f;
    const int d = e - 1;
    const bool doStore = (e >= D0 + 1);
    if (doStore && !zeroPrev) {
      size_t v0 = (size_t)d * HW + (size_t)(ty0 + py0) * WW + tx0 + px0;
      pr0 = *(const float2*)&prevBuf[v0];
      pr1 = *(const float2*)&prevBuf[v0 + WW];
    }
    if (live) comp_hidden(e);
    __syncthreads();  // hbuf RAW ready; all conv1 dbuf reads done
    if (live) {
      // scatter hidden e into aP(kz=0 -> e+1), aC(kz=1 -> e), aM(kz=2 -> e-1)
#pragma unroll 1
      for (int ch = 0; ch < 8; ++ch) {  // unroll 1: cap live set
        float hwf[4][4];
#pragma unroll
        for (int r = 0; r < 4; ++r) {
          const __fp16* hp = &hbuf[ch][py0 + r][px0];
          half2v a0 = *(const half2v*)hp;
          half2v a1 = *(const half2v*)(hp + 2);
          hwf[r][0] = (float)a0.x; hwf[r][1] = (float)a0.y;
          hwf[r][2] = (float)a1.x; hwf[r][3] = (float)a1.y;
        }
        const float* wch = w2 + ch * 27;
#pragma unroll
        for (int ky = 0; ky < 3; ++ky)
#pragma unroll
          for (int kx = 0; kx < 3; ++kx) {
            float w0 = wch[0 + ky * 3 + kx];
            float w1v = wch[9 + ky * 3 + kx];
            float w2v = wch[18 + ky * 3 + kx];
#pragma unroll
            for (int i = 0; i < 2; ++i)
#pragma unroll
              for (int j = 0; j < 2; ++j) {
                float h = hwf[i + ky][j + kx];
                aP[i][j] = fmaf(w0, h, aP[i][j]);
                aC[i][j] = fmaf(w1v, h, aC[i][j]);
                aM[i][j] = fmaf(w2v, h, aM[i][j]);
              }
          }
      }
    }
    // deriv plane e+2 -> LDS (slot (e+2)%3 == (e-1)%3, freed by the sync)
    write_deriv(e + 2);
    // plane e-1 complete after hidden e's kz=2 contribution
    if (doStore) {
      size_t v0 = (size_t)d * HW + (size_t)(ty0 + py0) * WW + tx0 + px0;
      float2 o0, o1;
      o0.x = pr0.x + coef * (pr0.x - aM[0][0]);
      o0.y = pr0.y + coef * (pr0.y - aM[0][1]);
      o1.x = pr1.x + coef * (pr1.x - aM[1][0]);
      o1.y = pr1.y + coef * (pr1.y - aM[1][1]);
      *(float2*)&outBuf[v0] = o0;
      *(float2*)&outBuf[v0 + WW] = o1;
    }
    // rotate ring (name rotation: no dynamic register indexing)
#pragma unroll
    for (int i = 0; i < 2; ++i)
#pragma unroll
      for (int j = 0; j < 2; ++j) {
        aM[i][j] = aC[i][j]; aC[i][j] = aP[i][j]; aP[i][j] = b2;
      }
    __syncthreads();  // fences dbuf RAW + hbuf WAR for next iteration
  }
}

// ---------------------------------------------------------------------------
// Kernel C: t_next = fdiff_t(p,x) + fdiff_t(q,y) + fdiff_t(s,z) + zb
// ---------------------------------------------------------------------------
__global__ __launch_bounds__(256) void k_combine(
    const float* __restrict__ p, const float* __restrict__ q,
    const float* __restrict__ s_, const float* __restrict__ zb,
    float* __restrict__ tn) {
  int idx = blockIdx.x * 256 + threadIdx.x;
  int x = idx & (WW - 1);
  int y = (idx >> 8) & (HH - 1);
  int d = idx >> 16;
  float v = zb[idx];
  v += (x > 0 ? p[idx - 1] : 0.f) - (x < WW - 1 ? p[idx] : 0.f);
  v += (y > 0 ? q[idx - WW] : 0.f) - (y < HH - 1 ? q[idx] : 0.f);
  v += (d > 0 ? s_[idx - HW] : 0.f) - (d < DD - 1 ? s_[idx] : 0.f);
  tn[idx] = v;
}

// ---------------------------------------------------------------------------
extern "C" void kernel_launch(void* const* d_in, const int* in_sizes, int n_in,
                              void* d_out, int out_size, void* d_ws, size_t ws_size,
                              hipStream_t stream) {
  const float* image = (const float*)d_in[0];
  const float* sino  = (const float*)d_in[1];
  const float* W1    = (const float*)d_in[2];
  const float* B1    = (const float*)d_in[3];
  const float* W2    = (const float*)d_in[4];
  const float* B2    = (const float*)d_in[5];
  const float* ntx   = (const float*)d_in[6];
  const float* nty   = (const float*)d_in[7];
  const float* ntz   = (const float*)d_in[8];
  const float* nt    = (const float*)d_in[9];
  float* out = (float*)d_out;

  // workspace layout: corr(HW) | p | q | s | zb  -> 67.4 MB total
  float* corr = (float*)d_ws;
  float* p  = corr + HW;
  float* q  = p + NVOX;
  float* s_ = q + NVOX;
  float* zb = s_ + NVOX;

  // outs[0] = image
  hipMemcpyAsync(out, image, (size_t)NVOX * sizeof(float),
                 hipMemcpyDeviceToDevice, stream);

  for (int c = 0; c < 3; ++c) {
    const float* t = out + (size_t)c * NVOX;
    float* tn = out + (size_t)(c + 1) * NVOX;
    k_corr<<<HW / 256, 256, 0, stream>>>(t, sino, corr);
    k_blocks<<<dim3(WW / TS, HH / TS, 16), 256, 0, stream>>>(
        t, corr, p, q, s_, zb, W1, B1, W2, B2, ntx, nty, ntz, nt, c);
    k_combine<<<NVOX / 256, 256, 0, stream>>>(p, q, s_, zb, tn);
  }
}

// Round 9
// 939.407 us; speedup vs baseline: 1.2590x; 1.0331x over previous
//
#include <hip/hip_runtime.h>

#define DD 64
#define HH 256
#define WW 256
#define HW (HH * WW)      // 65536
#define NVOX (DD * HW)    // 4194304

#define TS 32             // output tile (H and W)
#define DR 36             // deriv region = TS+4 (row stride 36, even)
#define HPH 40            // hbuf row stride in HALFS (bank-spread: 2-way free)
#define CHB 16            // depth chunk: 4 chunks -> grid z=16 -> 1024 blocks = 4/CU
#define NPF 6             // prefetch slots = ceil(DR*DR/256)

typedef __fp16 half2v __attribute__((ext_vector_type(2)));

// ---------------------------------------------------------------------------
// Kernel A: corr[h,w] = (sino[h,w] - sum_d t[d,h,w]) / DD
// ---------------------------------------------------------------------------
__global__ __launch_bounds__(256) void k_corr(const float* __restrict__ t,
                                              const float* __restrict__ sino,
                                              float* __restrict__ corr) {
  int idx = blockIdx.x * 256 + threadIdx.x;  // 0..HW-1
  float s = 0.f;
#pragma unroll 8
  for (int d = 0; d < DD; ++d) s += t[d * HW + idx];
  corr[idx] = (sino[idx] - s) * (1.0f / DD);
}

// ---------------------------------------------------------------------------
// Kernel B (R12 = R7c, session best: 944.5us total, k_blocks 304us).
// Plateau ledger (R6-R11): occupancy 2-4 blk/CU, LDS 37-53KB, VALU ops -25%,
// barriers 36->34, balance, VGPR 48-88 -- all land 304-313us. VALUBusy 80-84%
// + HBM ~5% + MfmaUtil 0 => compute-bound mixed-stall equilibrium; no
// remaining lever with EV > noise. This is the final configuration.
// ---------------------------------------------------------------------------
__global__ __launch_bounds__(256, 4) void k_blocks(
    const float* __restrict__ t, const float* __restrict__ corr,
    float* __restrict__ p, float* __restrict__ q, float* __restrict__ s_,
    float* __restrict__ zb,
    const float* __restrict__ W1g, const float* __restrict__ B1g,
    const float* __restrict__ W2g, const float* __restrict__ B2g,
    const float* __restrict__ ntx, const float* __restrict__ nty,
    const float* __restrict__ ntz, const float* __restrict__ nt, int c) {
  __shared__ __align__(16) float dbuf[3][DR][DR];        // 15552 B
  __shared__ __align__(16) __fp16 hbuf[8][34][HPH];      // 21760 B  (37312 total)

  const int b = blockIdx.z & 3;
  const int D0 = (blockIdx.z >> 2) * CHB;           // 0,16,32,48
  const int Dend = (D0 + CHB < DD) ? (D0 + CHB) : DD;
  const int ty0 = blockIdx.y * TS;
  const int tx0 = blockIdx.x * TS;
  const int tid = threadIdx.x;

  const float* w1 = W1g + b * 216;  // [8][3][3][3]
  const float* w2 = W2g + b * 216;  // [8][3][3][3] (W2 shape (4,1,8,3,3,3))
  float b1[8];
#pragma unroll
  for (int ch = 0; ch < 8; ++ch) b1[ch] = B1g[b * 8 + ch];
  const float b2 = B2g[b];
  const float coef = (b == 0) ? ntx[c] : (b == 1) ? nty[c] : (b == 2) ? ntz[c] : nt[c];
  const float* prevBuf = (b == 0) ? p : (b == 1) ? q : (b == 2) ? s_ : t;
  float* outBuf = (b == 0) ? p : (b == 1) ? q : (b == 2) ? s_ : zb;
  const bool zeroPrev = (c == 0) && (b < 3);
  const int strideA = (b == 0) ? 1 : (b == 1) ? WW : HW;

  auto dslot = [](int f) { return (f + 6) % 3; };

  // ---- hoisted per-slot geometry (f-invariant): cbt, load-mask bit, corr diff
  int cbt[NPF];
  float dC[NPF];
  unsigned mbits = 0;
#pragma unroll
  for (int k = 0; k < NPF; ++k) {
    int i = tid + k * 256;
    int iy = i / DR, ix = i - iy * DR;
    int gy = ty0 - 2 + iy, gx = tx0 - 2 + ix;
    bool inb = (i < DR * DR) && ((unsigned)gy < HH) && ((unsigned)gx < WW);
    int cb = gy * WW + gx;
    cbt[k] = cb;
    bool m;
    float d = 0.f;
    if (b == 0) {
      m = inb && (gx + 1 < WW);
      if (m) d = corr[cb + 1] - corr[cb];
    } else if (b == 1) {
      m = inb && (gy + 1 < HH);
      if (m) d = corr[cb + WW] - corr[cb];
    } else if (b == 2) {
      m = inb;
    } else {
      m = inb;
      if (m) d = corr[cb];
    }
    dC[k] = d;
    if (m) mbits |= (1u << k);
  }

  // ---- prefetch state: raw global t values for deriv plane f
  float pA0[NPF], pA1[NPF];

  auto issue_loads = [&](int f) {
    const bool fok = (f >= 0) && (f < DD) && (b != 2 || (f + 1 < DD));
    const int fb = f * HW;
#pragma unroll
    for (int k = 0; k < NPF; ++k) {
      pA0[k] = 0.f; pA1[k] = 0.f;
      if (fok && ((mbits >> k) & 1u)) {
        const float* base = t + fb + cbt[k];
        pA0[k] = base[0];
        if (b != 3) pA1[k] = base[strideA];
      }
    }
  };
  auto write_deriv = [&](int f) {
    float* dst = &dbuf[dslot(f)][0][0];
#pragma unroll
    for (int k = 0; k < NPF; ++k) {
      if (k < 5 || tid < (DR * DR - 5 * 256)) {  // i < 1296
        float v = (b == 3) ? (pA0[k] + dC[k]) : ((pA1[k] - pA0[k]) + dC[k]);
        dst[tid + k * 256] = v;
      }
    }
  };

  // ---- conv1 for one 2x2 hidden patch at (jy,jx), channels [ch0,ch1)
  auto conv1_patch = [&](const float* d0, const float* d1, const float* d2,
                         int jy, int jx, int ch0, int ch1) {
    float win[3][4][4];
#pragma unroll
    for (int r = 0; r < 4; ++r) {
      int off = (jy + r) * DR + jx;
      const float2* r0 = (const float2*)(d0 + off);
      const float2* r1 = (const float2*)(d1 + off);
      const float2* r2 = (const float2*)(d2 + off);
      float2 a, bb;
      a = r0[0]; bb = r0[1];
      win[0][r][0] = a.x; win[0][r][1] = a.y; win[0][r][2] = bb.x; win[0][r][3] = bb.y;
      a = r1[0]; bb = r1[1];
      win[1][r][0] = a.x; win[1][r][1] = a.y; win[1][r][2] = bb.x; win[1][r][3] = bb.y;
      a = r2[0]; bb = r2[1];
      win[2][r][0] = a.x; win[2][r][1] = a.y; win[2][r][2] = bb.x; win[2][r][3] = bb.y;
    }
    int gy0 = ty0 - 1 + jy, gx0 = tx0 - 1 + jx;
    bool in00 = ((unsigned)gy0 < HH) && ((unsigned)gx0 < WW);
    bool in01 = ((unsigned)gy0 < HH) && ((unsigned)(gx0 + 1) < WW);
    bool in10 = ((unsigned)(gy0 + 1) < HH) && ((unsigned)gx0 < WW);
    bool in11 = ((unsigned)(gy0 + 1) < HH) && ((unsigned)(gx0 + 1) < WW);
#pragma unroll 2
    for (int ch = ch0; ch < ch1; ++ch) {
      float bia = b1[ch];
      float a00 = bia, a01 = bia, a10 = bia, a11 = bia;
      const float* wch = w1 + ch * 27;
#pragma unroll
      for (int kz = 0; kz < 3; ++kz)
#pragma unroll
        for (int ky = 0; ky < 3; ++ky)
#pragma unroll
          for (int kx = 0; kx < 3; ++kx) {
            float wv = wch[kz * 9 + ky * 3 + kx];
            a00 = fmaf(wv, win[kz][ky][kx], a00);
            a01 = fmaf(wv, win[kz][ky][kx + 1], a01);
            a10 = fmaf(wv, win[kz][ky + 1][kx], a10);
            a11 = fmaf(wv, win[kz][ky + 1][kx + 1], a11);
          }
      half2v h0, h1;
      h0.x = (__fp16)(in00 ? fmaxf(a00, 0.f) : 0.f);
      h0.y = (__fp16)(in01 ? fmaxf(a01, 0.f) : 0.f);
      h1.x = (__fp16)(in10 ? fmaxf(a10, 0.f) : 0.f);
      h1.y = (__fp16)(in11 ? fmaxf(a11, 0.f) : 0.f);
      *(half2v*)&hbuf[ch][jy][jx] = h0;
      *(half2v*)&hbuf[ch][jy + 1][jx] = h1;
    }
  };

  // ---- hidden plane e -> hbuf. Balanced: phase1 256 patches (1/thread),
  // phase2 = 33 leftover patches x 4 ch-pairs = 132 tasks (1/thread).
  auto comp_hidden = [&](int e) {
    const float* d0 = &dbuf[dslot(e - 1)][0][0];
    const float* d1 = &dbuf[dslot(e)][0][0];
    const float* d2 = &dbuf[dslot(e + 1)][0][0];
    {
      int prr = tid / 17, pcc = tid - prr * 17;     // patches 0..255
      conv1_patch(d0, d1, d2, prr * 2, pcc * 2, 0, 8);
    }
    if (tid < 132) {                                 // patches 256..288
      int m = tid >> 2, chp = (tid & 3) << 1;
      int pi = 256 + m;
      int prr = pi / 17, pcc = pi - prr * 17;
      conv1_patch(d0, d1, d2, prr * 2, pcc * 2, chp, chp + 2);
    }
  };

  const int txi = tid & 15, tyi = tid >> 4;
  const int px0 = txi * 2, py0 = tyi * 2;

  // register ring: aM = plane e-1, aC = plane e, aP = plane e+1
  float aM[2][2], aC[2][2], aP[2][2];
#pragma unroll
  for (int i = 0; i < 2; ++i)
#pragma unroll
    for (int j = 0; j < 2; ++j) { aM[i][j] = b2; aC[i][j] = b2; aP[i][j] = b2; }

  // prologue: deriv planes D0-2, D0-1, D0 (out-of-range -> zeros)
  issue_loads(D0 - 2); write_deriv(D0 - 2);
  issue_loads(D0 - 1); write_deriv(D0 - 1);
  issue_loads(D0);     write_deriv(D0);
  __syncthreads();

  for (int e = D0 - 1; e <= Dend; ++e) {
    const bool live = (e >= 0 && e < DD);
    // prefetch next deriv plane (global -> regs); overlaps conv1 compute
    issue_loads(e + 2);
    // prefetch prev-state operand for this iteration's output store
    float2 pr0, pr1;
    pr0.x = pr0.y = pr1.x = pr1.y = 0.f;
    const int d = e - 1;
    const bool doStore = (e >= D0 + 1);
    if (doStore && !zeroPrev) {
      size_t v0 = (size_t)d * HW + (size_t)(ty0 + py0) * WW + tx0 + px0;
      pr0 = *(const float2*)&prevBuf[v0];
      pr1 = *(const float2*)&prevBuf[v0 + WW];
    }
    if (live) comp_hidden(e);
    __syncthreads();  // hbuf RAW ready; all conv1 dbuf reads done
    if (live) {
      // scatter hidden e into aP(kz=0 -> e+1), aC(kz=1 -> e), aM(kz=2 -> e-1)
#pragma unroll 1
      for (int ch = 0; ch < 8; ++ch) {  // unroll 1: cap live set
        float hwf[4][4];
#pragma unroll
        for (int r = 0; r < 4; ++r) {
          const __fp16* hp = &hbuf[ch][py0 + r][px0];
          half2v a0 = *(const half2v*)hp;
          half2v a1 = *(const half2v*)(hp + 2);
          hwf[r][0] = (float)a0.x; hwf[r][1] = (float)a0.y;
          hwf[r][2] = (float)a1.x; hwf[r][3] = (float)a1.y;
        }
        const float* wch = w2 + ch * 27;
#pragma unroll
        for (int ky = 0; ky < 3; ++ky)
#pragma unroll
          for (int kx = 0; kx < 3; ++kx) {
            float w0 = wch[0 + ky * 3 + kx];
            float w1v = wch[9 + ky * 3 + kx];
            float w2v = wch[18 + ky * 3 + kx];
#pragma unroll
            for (int i = 0; i < 2; ++i)
#pragma unroll
              for (int j = 0; j < 2; ++j) {
                float h = hwf[i + ky][j + kx];
                aP[i][j] = fmaf(w0, h, aP[i][j]);
                aC[i][j] = fmaf(w1v, h, aC[i][j]);
                aM[i][j] = fmaf(w2v, h, aM[i][j]);
              }
          }
      }
    }
    // deriv plane e+2 -> LDS (slot (e+2)%3 == (e-1)%3, freed by the sync)
    write_deriv(e + 2);
    // plane e-1 complete after hidden e's kz=2 contribution
    if (doStore) {
      size_t v0 = (size_t)d * HW + (size_t)(ty0 + py0) * WW + tx0 + px0;
      float2 o0, o1;
      o0.x = pr0.x + coef * (pr0.x - aM[0][0]);
      o0.y = pr0.y + coef * (pr0.y - aM[0][1]);
      o1.x = pr1.x + coef * (pr1.x - aM[1][0]);
      o1.y = pr1.y + coef * (pr1.y - aM[1][1]);
      *(float2*)&outBuf[v0] = o0;
      *(float2*)&outBuf[v0 + WW] = o1;
    }
    // rotate ring (name rotation: no dynamic register indexing)
#pragma unroll
    for (int i = 0; i < 2; ++i)
#pragma unroll
      for (int j = 0; j < 2; ++j) {
        aM[i][j] = aC[i][j]; aC[i][j] = aP[i][j]; aP[i][j] = b2;
      }
    __syncthreads();  // fences dbuf RAW + hbuf WAR for next iteration
  }
}

// ---------------------------------------------------------------------------
// Kernel C: t_next = fdiff_t(p,x) + fdiff_t(q,y) + fdiff_t(s,z) + zb
// ---------------------------------------------------------------------------
__global__ __launch_bounds__(256) void k_combine(
    const float* __restrict__ p, const float* __restrict__ q,
    const float* __restrict__ s_, const float* __restrict__ zb,
    float* __restrict__ tn) {
  int idx = blockIdx.x * 256 + threadIdx.x;
  int x = idx & (WW - 1);
  int y = (idx >> 8) & (HH - 1);
  int d = idx >> 16;
  float v = zb[idx];
  v += (x > 0 ? p[idx - 1] : 0.f) - (x < WW - 1 ? p[idx] : 0.f);
  v += (y > 0 ? q[idx - WW] : 0.f) - (y < HH - 1 ? q[idx] : 0.f);
  v += (d > 0 ? s_[idx - HW] : 0.f) - (d < DD - 1 ? s_[idx] : 0.f);
  tn[idx] = v;
}

// ---------------------------------------------------------------------------
extern "C" void kernel_launch(void* const* d_in, const int* in_sizes, int n_in,
                              void* d_out, int out_size, void* d_ws, size_t ws_size,
                              hipStream_t stream) {
  const float* image = (const float*)d_in[0];
  const float* sino  = (const float*)d_in[1];
  const float* W1    = (const float*)d_in[2];
  const float* B1    = (const float*)d_in[3];
  const float* W2    = (const float*)d_in[4];
  const float* B2    = (const float*)d_in[5];
  const float* ntx   = (const float*)d_in[6];
  const float* nty   = (const float*)d_in[7];
  const float* ntz   = (const float*)d_in[8];
  const float* nt    = (const float*)d_in[9];
  float* out = (float*)d_out;

  // workspace layout: corr(HW) | p | q | s | zb  -> 67.4 MB total
  float* corr = (float*)d_ws;
  float* p  = corr + HW;
  float* q  = p + NVOX;
  float* s_ = q + NVOX;
  float* zb = s_ + NVOX;

  // outs[0] = image
  hipMemcpyAsync(out, image, (size_t)NVOX * sizeof(float),
                 hipMemcpyDeviceToDevice, stream);

  for (int c = 0; c < 3; ++c) {
    const float* t = out + (size_t)c * NVOX;
    float* tn = out + (size_t)(c + 1) * NVOX;
    k_corr<<<HW / 256, 256, 0, stream>>>(t, sino, corr);
    // z: 4 basic-blocks x 4 depth chunks -> 1024 blocks = 4 WG/CU
    k_blocks<<<dim3(WW / TS, HH / TS, 16), 256, 0, stream>>>(
        t, corr, p, q, s_, zb, W1, B1, W2, B2, ntx, nty, ntz, nt, c);
    k_combine<<<NVOX / 256, 256, 0, stream>>>(p, q, s_, zb, tn);
  }
}